// Round 12
// baseline (82.045 us; speedup 1.0000x reference)
//
#include <hip/hip_runtime.h>
#include <math.h>

#define HW     262144   // 512*512
#define WIDTH  512
#define BB     4
#define NN     32
#define KK     256
#define PP     8192
#define EPSF   1e-4f
#define ONE_M_EPS (1.0f - 1e-4f)

// ---- block partition: inst first (longest), small families fill the tail ----
#define NBLK_INST  512   // (b:4) x (grp:4 of 8 inst) x (seg:32 of 32KB plane-segment)
#define NBLK_WH    256
#define NBLK_FOCAL 512   // 2 tensors x 256
#define NBLK_TAN   32
#define NBLK_VAR   128
#define OFF_WH     NBLK_INST
#define OFF_FOCAL  (OFF_WH + NBLK_WH)
#define OFF_TAN    (OFF_FOCAL + NBLK_FOCAL)
#define OFF_VAR    (OFF_TAN + NBLK_TAN)
#define NBLK_TOTAL (OFF_VAR + NBLK_VAR)   // 1440

// ---- workspace layout (floats) ----
#define WS_INST  0       // [512 blocks][16]  (il*2 + {sum,cnt}) = 8192
#define WS_FOCAL 8192    // [2][256][2] = 1024
#define WS_WH    9216    // [256][2]    = 512
#define WS_TAN   9728    // [32]
#define WS_VAR   9760    // [128]
// total 9888 floats

__device__ __forceinline__ float ftanh(float x) {
    float e = __expf(2.0f * x);
    return 1.0f - 2.0f / (e + 1.0f);
}

__device__ __forceinline__ float wave_reduce(float v) {
    #pragma unroll
    for (int off = 1; off < 64; off <<= 1) v += __shfl_xor(v, off, 64);
    return v;
}

__device__ __forceinline__ float block_reduce(float v, float* sbuf) {
    v = wave_reduce(v);
    int lane = threadIdx.x & 63, wid = threadIdx.x >> 6;
    __syncthreads();
    if (lane == 0) sbuf[wid] = v;
    __syncthreads();
    float r = 0.f;
    if (threadIdx.x == 0) {
        for (int i = 0; i < 4; ++i) r += sbuf[i];
    }
    return r;
}

// ---- AE instance focal: R10 geometry + loop interchange (se/sg once/pixel) ----
// idx: b = idx>>7, grp = (idx>>5)&3 (8 instances), seg = idx&31 (32KB segments).
// Per it (4KB step): load ae f4, compute se/sg ONCE (6 trans / 8 instances),
// then 2 half-batches of 4 mask-plane loads -> accumulate a_sum[8]/a_cnt[8].
// Mask streams stay sequential within the 32KB segment (4KB interleave).
__device__ __forceinline__ void inst_part(int idx, const float* __restrict__ ae,
                                          const float* __restrict__ masks,
                                          const int* __restrict__ centers,
                                          float* __restrict__ ws,
                                          float* __restrict__ s_part) { // [4][16]
    const int tid = threadIdx.x, lane = tid & 63, w = tid >> 6;
    const int b = idx >> 7, grp = (idx >> 5) & 3, seg = idx & 31;
    const float4* aeb   = (const float4*)ae + (size_t)b * 4 * 65536;
    const float4* mbase = (const float4*)masks + ((size_t)(b * NN + grp * 8) << 16);
    const int segf4 = seg * 2048;     // 2048 f4 = 32KB
    const int* cb = centers + (b * NN + grp * 8) * 2;

    float cy[8], cx[8];
    #pragma unroll
    for (int il = 0; il < 8; ++il) {
        cy[il] = (float)cb[il * 2]     * (1.0f / 512.0f);   // wave-uniform
        cx[il] = (float)cb[il * 2 + 1] * (1.0f / 512.0f);
    }
    float a_sum[8] = {0.f, 0.f, 0.f, 0.f, 0.f, 0.f, 0.f, 0.f};
    float a_cnt[8] = {0.f, 0.f, 0.f, 0.f, 0.f, 0.f, 0.f, 0.f};

    #pragma unroll
    for (int it = 0; it < 8; ++it) {
        int v = segf4 + it * 256 + tid;
        float4 a0 = aeb[v];
        float4 a1 = aeb[65536 + v];
        float4 a2 = aeb[131072 + v];
        float4 a3 = aeb[196608 + v];
        int pix0 = v * 4;
        float fy  = (float)(pix0 >> 9)  * (1.0f / 512.0f);
        float fx0 = (float)(pix0 & 511) * (1.0f / 512.0f);
        float se0[4], se1[4], sg0[4], sg1[4];
        #pragma unroll
        for (int j = 0; j < 4; ++j) {
            se0[j] = ftanh((&a0.x)[j]) + fy;
            se1[j] = ftanh((&a1.x)[j]) + fx0 + (float)j * (1.0f / 512.0f);
            sg0[j] = __expf((&a2.x)[j]);
            sg1[j] = __expf((&a3.x)[j]);
        }
        #pragma unroll
        for (int h = 0; h < 2; ++h) {
            float4 mk[4];   // 4 independent mask-plane loads (16 VGPR)
            #pragma unroll
            for (int i = 0; i < 4; ++i)
                mk[i] = mbase[((size_t)(h * 4 + i) << 16) + v];
            #pragma unroll
            for (int i = 0; i < 4; ++i) {
                int il = h * 4 + i;
                float ccy = cy[il], ccx = cx[il];
                #pragma unroll
                for (int j = 0; j < 4; ++j) {
                    float m  = (&mk[i].x)[j];              // exactly 0.0 or 1.0
                    float dy = se0[j] - ccy, dx = se1[j] - ccx;
                    float s  = fmaf(dx * dx, sg1[j], dy * dy * sg0[j]);
                    float e  = __expf(-s);
                    float pc = fminf(fmaxf(e, EPSF), ONE_M_EPS);
                    float omp = 1.0f - pc;
                    // pos: log(pc)*omp^2 ; neg: log(omp)*pc^2 (neg_w==1, binary)
                    float A = (m != 0.f) ? pc : omp;
                    float B = 1.0f - A;
                    a_sum[il] = fmaf(__logf(A), B * B, a_sum[il]);
                    a_cnt[il] += m;
                }
            }
        }
    }
    #pragma unroll
    for (int il = 0; il < 8; ++il) {
        float r0 = wave_reduce(a_sum[il]);
        float r1 = wave_reduce(a_cnt[il]);
        if (lane == 0) {
            s_part[w * 16 + il * 2 + 0] = r0;
            s_part[w * 16 + il * 2 + 1] = r1;
        }
    }
    __syncthreads();
    if (tid < 16) {
        float s = s_part[tid] + s_part[16 + tid] + s_part[32 + tid] + s_part[48 + tid];
        ws[WS_INST + idx * 16 + tid] = s;
    }
}

// ---- cls/kp focal: idx = t*256 + blk, 4 iters ----
__device__ __forceinline__ void focal_part(int idx, const float* __restrict__ cls_out,
                                           const float* __restrict__ cls_mask,
                                           const float* __restrict__ kp_out,
                                           const float* __restrict__ kp_mask,
                                           float* __restrict__ ws, float* sbuf) {
    int t = idx >> 8, blk = idx & 255;
    const float4* po = (const float4*)(t == 0 ? cls_out : kp_out);
    const float4* pm = (const float4*)(t == 0 ? cls_mask : kp_mask);
    float sum = 0.f, cnt = 0.f;
    #pragma unroll
    for (int it = 0; it < 4; ++it) {
        int i = blk * 256 + threadIdx.x + it * 65536;
        float4 xo = po[i], xm = pm[i];
        #pragma unroll
        for (int j = 0; j < 4; ++j) {
            float x = (&xo.x)[j], gt = (&xm.x)[j];
            float p = 1.0f / (1.0f + __expf(-x));
            p = fminf(fmaxf(p, EPSF), ONE_M_EPS);
            float omp = 1.0f - p;
            float pos_t = __logf(p) * omp * omp;
            float og = 1.0f - gt;
            float negw = og * og; negw *= negw;
            float neg_t = __logf(omp) * p * p * negw;
            bool ispos = (gt == 1.0f);
            sum += ispos ? pos_t : neg_t;
            cnt += ispos ? 1.0f : 0.0f;
        }
    }
    float r0 = block_reduce(sum, sbuf);
    float r1 = block_reduce(cnt, sbuf);
    if (threadIdx.x == 0) {
        ws[WS_FOCAL + idx * 2 + 0] = r0;
        ws[WS_FOCAL + idx * 2 + 1] = r1;
    }
}

__device__ __forceinline__ void wh_part(int blk, const float* __restrict__ o,
                                        const float* __restrict__ tg,
                                        const float* __restrict__ m,
                                        float* __restrict__ ws, float* sbuf) {
    const float4* po  = (const float4*)o;
    const float4* pt  = (const float4*)tg;
    const float4* pmk = (const float4*)m;
    float sl = 0.f, ms = 0.f;
    #pragma unroll
    for (int it = 0; it < 8; ++it) {
        int i = blk * 256 + threadIdx.x + it * 65536;
        float4 a = po[i], b = pt[i], c = pmk[i];
        #pragma unroll
        for (int j = 0; j < 4; ++j) {
            float mm = (&c.x)[j];
            float d  = (&a.x)[j] * mm - (&b.x)[j] * mm;
            float ad = fabsf(d);
            sl += (ad < 1.0f) ? 0.5f * d * d : (ad - 0.5f);
            ms += mm;
        }
    }
    float r0 = block_reduce(sl, sbuf);
    float r1 = block_reduce(ms, sbuf);
    if (threadIdx.x == 0) {
        ws[WS_WH + blk * 2 + 0] = r0;
        ws[WS_WH + blk * 2 + 1] = r1;
    }
}

__device__ __forceinline__ void tan_part(int idx, const float* __restrict__ tan_out,
                                         const float* __restrict__ normals,
                                         const int* __restrict__ pts,
                                         float* __restrict__ ws, float* sbuf) {
    int b = idx >> 3, seg = idx & 7;
    float s = 0.f;
    for (int p = seg * 1024 + threadIdx.x; p < seg * 1024 + 1024; p += 256) {
        int base = (b * PP + p) * 2;
        int py = pts[base], px = pts[base + 1];
        int pix = py * WIDTH + px;
        float t0 = tan_out[b * 2 * HW + pix];
        float t1 = tan_out[b * 2 * HW + HW + pix];
        float inv = 1.0f / fmaxf(sqrtf(t0 * t0 + t1 * t1), EPSF);
        float n0 = normals[base], n1 = normals[base + 1];
        s += 1.0f - (n0 * t0 + n1 * t1) * inv;
    }
    float r = block_reduce(s, sbuf);
    if (threadIdx.x == 0) ws[WS_TAN + idx] = r;
}

__device__ __forceinline__ void var_part(int idx, const float* __restrict__ ae,
                                         const int* __restrict__ centers,
                                         const int* __restrict__ kps,
                                         float* __restrict__ ws, float* smem) {
    int n = idx & 31, b = idx >> 5;
    float* cy = smem, *cx = smem + 32, *sbuf = smem + 64;
    if (threadIdx.x < NN) {
        int cb = (b * NN + threadIdx.x) * 2;
        cy[threadIdx.x] = centers[cb]     * (1.0f / 512.0f);
        cx[threadIdx.x] = centers[cb + 1] * (1.0f / 512.0f);
    }
    __syncthreads();
    int k = threadIdx.x;
    int kb = ((b * NN + n) * KK + k) * 2;
    int ky = kps[kb], kx = kps[kb + 1];
    int pix = ky * WIDTH + kx;
    const float* aeb = ae + (size_t)b * 4 * HW;
    float se0 = ftanh(aeb[pix])      + ky * (1.0f / 512.0f);
    float se1 = ftanh(aeb[HW + pix]) + kx * (1.0f / 512.0f);
    float sg0 = __expf(aeb[2 * HW + pix]);
    float sg1 = __expf(aeb[3 * HW + pix]);
    float own = 0.f, mx = -1e30f;
    #pragma unroll
    for (int m = 0; m < NN; ++m) {
        float d0 = se0 - cy[m], d1 = se1 - cx[m];
        float dist = __expf(-(d0 * d0 * sg0 + d1 * d1 * sg1));
        mx = fmaxf(mx, dist);
        if (m == n) own = dist;
    }
    float r = block_reduce(fabsf(own - mx), sbuf);
    if (threadIdx.x == 0) ws[WS_VAR + b * NN + n] = r;
}

// ---- the mega kernel: one dispatch for all partials ----
__global__ void __launch_bounds__(256)
k_mega(const float* __restrict__ cls_out, const float* __restrict__ wh_out,
       const float* __restrict__ kp_out,  const float* __restrict__ ae_out,
       const float* __restrict__ tan_out, const float* __restrict__ cls_mask,
       const float* __restrict__ wh_target, const float* __restrict__ wh_mask,
       const float* __restrict__ kp_mask, const float* __restrict__ ae_masks,
       const float* __restrict__ tan_normals,
       const int* __restrict__ centers, const int* __restrict__ kps,
       const int* __restrict__ tan_points, float* __restrict__ ws) {
    __shared__ float smem[256];
    int bid = blockIdx.x;
    if (bid < NBLK_INST) {
        inst_part(bid, ae_out, ae_masks, centers, ws, smem);
    } else if (bid < OFF_FOCAL) {
        wh_part(bid - OFF_WH, wh_out, wh_target, wh_mask, ws, smem);
    } else if (bid < OFF_TAN) {
        focal_part(bid - OFF_FOCAL, cls_out, cls_mask, kp_out, kp_mask, ws, smem);
    } else if (bid < OFF_VAR) {
        tan_part(bid - OFF_TAN, tan_out, tan_normals, tan_points, ws, smem);
    } else {
        var_part(bid - OFF_VAR, ae_out, centers, kps, ws, smem);
    }
}

// ---- finalize: 1 block ----
__global__ void __launch_bounds__(256)
k_final(const float* __restrict__ ws, float* __restrict__ out) {
    __shared__ float sbuf[4];
    int tid = threadIdx.x;
    float ae_v = 0.f;
    if (tid < 128) {   // tid = b*32 + n ; n = grp*8 + i
        int b = tid >> 5, n = tid & 31, grp = n >> 3, i = n & 7;
        const float* base = ws + WS_INST + ((b * 4 + grp) * 32) * 16 + i * 2;
        float sum = 0.f, cnt = 0.f;
        #pragma unroll 8
        for (int seg = 0; seg < 32; ++seg) { sum += base[seg * 16]; cnt += base[seg * 16 + 1]; }
        // where(np>0, -(pos+neg)/max(np,1), -neg) == -sum/max(np,1)  (np==0 => pos==0)
        ae_v = -sum / fmaxf(cnt, 1.0f) + ws[WS_VAR + tid];
    }
    float ae_sum = block_reduce(ae_v, sbuf);

    float cls_sum = block_reduce(ws[WS_FOCAL + tid * 2], sbuf);
    float cls_cnt = block_reduce(ws[WS_FOCAL + tid * 2 + 1], sbuf);
    float kp_sum  = block_reduce(ws[WS_FOCAL + 512 + tid * 2], sbuf);
    float kp_cnt  = block_reduce(ws[WS_FOCAL + 512 + tid * 2 + 1], sbuf);
    float wh_sl   = block_reduce(ws[WS_WH + tid * 2], sbuf);
    float wh_ms   = block_reduce(ws[WS_WH + tid * 2 + 1], sbuf);
    float tan_sum = block_reduce(tid < 32 ? ws[WS_TAN + tid] : 0.f, sbuf);

    if (tid == 0) {
        float l_cls = -cls_sum / fmaxf(cls_cnt, 1.0f);
        float l_kp  = -kp_sum  / fmaxf(kp_cnt,  1.0f);
        float l_wh  = 0.1f * wh_sl / (wh_ms + 1e-4f);
        float l_ae  = ae_sum / (float)(NN * BB);
        float l_tan = tan_sum / (float)(PP * BB);
        out[0] = l_cls + l_wh + l_kp + l_ae + l_tan;
    }
}

extern "C" void kernel_launch(void* const* d_in, const int* in_sizes, int n_in,
                              void* d_out, int out_size, void* d_ws, size_t ws_size,
                              hipStream_t stream) {
    const float* cls_out     = (const float*)d_in[0];
    const float* wh_out      = (const float*)d_in[1];
    const float* kp_out      = (const float*)d_in[2];
    const float* ae_out      = (const float*)d_in[3];
    const float* tan_out     = (const float*)d_in[4];
    const float* cls_mask    = (const float*)d_in[5];
    const float* wh_target   = (const float*)d_in[6];
    const float* wh_mask     = (const float*)d_in[7];
    const float* kp_mask     = (const float*)d_in[8];
    const float* ae_masks    = (const float*)d_in[9];
    const float* tan_normals = (const float*)d_in[10];
    // d_in[11] = xym: analytic (y/512, x/512)
    const int* centers    = (const int*)d_in[12];
    const int* kps        = (const int*)d_in[13];
    const int* tan_points = (const int*)d_in[14];
    float* ws  = (float*)d_ws;
    float* out = (float*)d_out;

    k_mega<<<NBLK_TOTAL, 256, 0, stream>>>(cls_out, wh_out, kp_out, ae_out, tan_out,
                                           cls_mask, wh_target, wh_mask, kp_mask,
                                           ae_masks, tan_normals, centers, kps,
                                           tan_points, ws);
    k_final<<<1, 256, 0, stream>>>(ws, out);
}

// Round 13
// 67.875 us; speedup vs baseline: 1.2088x; 1.2088x over previous
//
#include <hip/hip_runtime.h>
#include <math.h>

#define HW     262144   // 512*512
#define WIDTH  512
#define BB     4
#define NN     32
#define KK     256
#define PP     8192
#define EPSF   1e-4f
#define ONE_M_EPS (1.0f - 1e-4f)

// ---- block partition: inst first (longest), small families fill the tail ----
#define NBLK_INST  1024  // (b:4) x (grp:4 of 8 inst) x (seg:64 of 16KB plane-segment)
#define NBLK_WH    256
#define NBLK_FOCAL 512   // 2 tensors x 256
#define NBLK_TAN   32
#define NBLK_VAR   128
#define OFF_WH     NBLK_INST
#define OFF_FOCAL  (OFF_WH + NBLK_WH)
#define OFF_TAN    (OFF_FOCAL + NBLK_FOCAL)
#define OFF_VAR    (OFF_TAN + NBLK_TAN)
#define NBLK_TOTAL (OFF_VAR + NBLK_VAR)   // 1952

// ---- workspace layout (floats) ----
#define WS_INST  0       // [1024 blocks][16]  (ilp*4 + par*2 + {sum,cnt}) = 16384
#define WS_FOCAL 16384   // [2][256][2] = 1024
#define WS_WH    17408   // [256][2]    = 512
#define WS_TAN   17920   // [32]
#define WS_VAR   17952   // [128]
// total 18080 floats

__device__ __forceinline__ float ftanh(float x) {
    float e = __expf(2.0f * x);
    return 1.0f - 2.0f / (e + 1.0f);
}

__device__ __forceinline__ float wave_reduce(float v) {
    #pragma unroll
    for (int off = 1; off < 64; off <<= 1) v += __shfl_xor(v, off, 64);
    return v;
}

__device__ __forceinline__ float block_reduce(float v, float* sbuf) {
    v = wave_reduce(v);
    int lane = threadIdx.x & 63, wid = threadIdx.x >> 6;
    __syncthreads();
    if (lane == 0) sbuf[wid] = v;
    __syncthreads();
    float r = 0.f;
    if (threadIdx.x == 0) {
        for (int i = 0; i < 4; ++i) r += sbuf[i];
    }
    return r;
}

// ---- AE instance focal: R10 geometry, instances processed in PAIRS ----
// idx: b = idx>>8, grp = (idx>>6)&3 (8 instances), seg = idx&63 (16KB segment).
// Per pair (4 pairs): sweep the 16KB segment (4 x 4KB steps, unroll 1);
// se/sg computed once per pixel per PAIR (4x trans redundancy vs R10's 8x);
// two sequential mask streams; only 4 accumulators + 2 mask regs live.
// ae traffic: 4 sweeps x 64KB = 256KB/block (vs R10 1MB/block).
__device__ __forceinline__ void inst_part(int idx, const float* __restrict__ ae,
                                          const float* __restrict__ masks,
                                          const int* __restrict__ centers,
                                          float* __restrict__ ws,
                                          float* __restrict__ s_part) { // [4][16]
    const int tid = threadIdx.x, lane = tid & 63, w = tid >> 6;
    const int b = idx >> 8, grp = (idx >> 6) & 3, seg = idx & 63;
    const float4* aeb   = (const float4*)ae + (size_t)b * 4 * 65536;
    const float4* mbase = (const float4*)masks + ((size_t)(b * NN + grp * 8) << 16);
    const int segf4 = seg * 1024;     // 1024 f4 = 16KB
    const int* cb = centers + (b * NN + grp * 8) * 2;

    #pragma unroll 1
    for (int ilp = 0; ilp < 4; ++ilp) {
        int il0 = ilp * 2, il1 = ilp * 2 + 1;
        float cy0 = (float)cb[il0 * 2]     * (1.0f / 512.0f);   // wave-uniform
        float cx0 = (float)cb[il0 * 2 + 1] * (1.0f / 512.0f);
        float cy1 = (float)cb[il1 * 2]     * (1.0f / 512.0f);
        float cx1 = (float)cb[il1 * 2 + 1] * (1.0f / 512.0f);
        const float4* mp0 = mbase + ((size_t)il0 << 16) + segf4;
        const float4* mp1 = mbase + ((size_t)il1 << 16) + segf4;
        float sum0 = 0.f, cnt0 = 0.f, sum1 = 0.f, cnt1 = 0.f;
        #pragma unroll 1
        for (int it = 0; it < 4; ++it) {
            int o = it * 256 + tid;
            float4 mk0 = mp0[o];
            float4 mk1 = mp1[o];
            int v = segf4 + o;
            float4 a0 = aeb[v];
            float4 a1 = aeb[65536 + v];
            float4 a2 = aeb[131072 + v];
            float4 a3 = aeb[196608 + v];
            int pix0 = v * 4;
            float fy  = (float)(pix0 >> 9)  * (1.0f / 512.0f);
            float fx0 = (float)(pix0 & 511) * (1.0f / 512.0f);
            #pragma unroll
            for (int j = 0; j < 4; ++j) {
                float se0 = ftanh((&a0.x)[j]) + fy;
                float se1 = ftanh((&a1.x)[j]) + fx0 + (float)j * (1.0f / 512.0f);
                float sg0 = __expf((&a2.x)[j]);
                float sg1 = __expf((&a3.x)[j]);
                // instance il0
                {
                    float m  = (&mk0.x)[j];                // exactly 0.0 or 1.0
                    float dy = se0 - cy0, dx = se1 - cx0;
                    float s  = fmaf(dx * dx, sg1, dy * dy * sg0);
                    float e  = __expf(-s);
                    float pc = fminf(fmaxf(e, EPSF), ONE_M_EPS);
                    float omp = 1.0f - pc;
                    float A = (m != 0.f) ? pc : omp;
                    float B = 1.0f - A;
                    sum0 = fmaf(__logf(A), B * B, sum0);
                    cnt0 += m;
                }
                // instance il1
                {
                    float m  = (&mk1.x)[j];
                    float dy = se0 - cy1, dx = se1 - cx1;
                    float s  = fmaf(dx * dx, sg1, dy * dy * sg0);
                    float e  = __expf(-s);
                    float pc = fminf(fmaxf(e, EPSF), ONE_M_EPS);
                    float omp = 1.0f - pc;
                    float A = (m != 0.f) ? pc : omp;
                    float B = 1.0f - A;
                    sum1 = fmaf(__logf(A), B * B, sum1);
                    cnt1 += m;
                }
            }
        }
        float r0 = wave_reduce(sum0);
        float r1 = wave_reduce(cnt0);
        float r2 = wave_reduce(sum1);
        float r3 = wave_reduce(cnt1);
        if (lane == 0) {
            s_part[w * 16 + ilp * 4 + 0] = r0;
            s_part[w * 16 + ilp * 4 + 1] = r1;
            s_part[w * 16 + ilp * 4 + 2] = r2;
            s_part[w * 16 + ilp * 4 + 3] = r3;
        }
    }
    __syncthreads();
    if (tid < 16) {
        float s = s_part[tid] + s_part[16 + tid] + s_part[32 + tid] + s_part[48 + tid];
        ws[WS_INST + idx * 16 + tid] = s;
    }
}

// ---- cls/kp focal: idx = t*256 + blk, 4 iters ----
__device__ __forceinline__ void focal_part(int idx, const float* __restrict__ cls_out,
                                           const float* __restrict__ cls_mask,
                                           const float* __restrict__ kp_out,
                                           const float* __restrict__ kp_mask,
                                           float* __restrict__ ws, float* sbuf) {
    int t = idx >> 8, blk = idx & 255;
    const float4* po = (const float4*)(t == 0 ? cls_out : kp_out);
    const float4* pm = (const float4*)(t == 0 ? cls_mask : kp_mask);
    float sum = 0.f, cnt = 0.f;
    #pragma unroll
    for (int it = 0; it < 4; ++it) {
        int i = blk * 256 + threadIdx.x + it * 65536;
        float4 xo = po[i], xm = pm[i];
        #pragma unroll
        for (int j = 0; j < 4; ++j) {
            float x = (&xo.x)[j], gt = (&xm.x)[j];
            float p = 1.0f / (1.0f + __expf(-x));
            p = fminf(fmaxf(p, EPSF), ONE_M_EPS);
            float omp = 1.0f - p;
            float pos_t = __logf(p) * omp * omp;
            float og = 1.0f - gt;
            float negw = og * og; negw *= negw;
            float neg_t = __logf(omp) * p * p * negw;
            bool ispos = (gt == 1.0f);
            sum += ispos ? pos_t : neg_t;
            cnt += ispos ? 1.0f : 0.0f;
        }
    }
    float r0 = block_reduce(sum, sbuf);
    float r1 = block_reduce(cnt, sbuf);
    if (threadIdx.x == 0) {
        ws[WS_FOCAL + idx * 2 + 0] = r0;
        ws[WS_FOCAL + idx * 2 + 1] = r1;
    }
}

__device__ __forceinline__ void wh_part(int blk, const float* __restrict__ o,
                                        const float* __restrict__ tg,
                                        const float* __restrict__ m,
                                        float* __restrict__ ws, float* sbuf) {
    const float4* po  = (const float4*)o;
    const float4* pt  = (const float4*)tg;
    const float4* pmk = (const float4*)m;
    float sl = 0.f, ms = 0.f;
    #pragma unroll
    for (int it = 0; it < 8; ++it) {
        int i = blk * 256 + threadIdx.x + it * 65536;
        float4 a = po[i], b = pt[i], c = pmk[i];
        #pragma unroll
        for (int j = 0; j < 4; ++j) {
            float mm = (&c.x)[j];
            float d  = (&a.x)[j] * mm - (&b.x)[j] * mm;
            float ad = fabsf(d);
            sl += (ad < 1.0f) ? 0.5f * d * d : (ad - 0.5f);
            ms += mm;
        }
    }
    float r0 = block_reduce(sl, sbuf);
    float r1 = block_reduce(ms, sbuf);
    if (threadIdx.x == 0) {
        ws[WS_WH + blk * 2 + 0] = r0;
        ws[WS_WH + blk * 2 + 1] = r1;
    }
}

__device__ __forceinline__ void tan_part(int idx, const float* __restrict__ tan_out,
                                         const float* __restrict__ normals,
                                         const int* __restrict__ pts,
                                         float* __restrict__ ws, float* sbuf) {
    int b = idx >> 3, seg = idx & 7;
    float s = 0.f;
    for (int p = seg * 1024 + threadIdx.x; p < seg * 1024 + 1024; p += 256) {
        int base = (b * PP + p) * 2;
        int py = pts[base], px = pts[base + 1];
        int pix = py * WIDTH + px;
        float t0 = tan_out[b * 2 * HW + pix];
        float t1 = tan_out[b * 2 * HW + HW + pix];
        float inv = 1.0f / fmaxf(sqrtf(t0 * t0 + t1 * t1), EPSF);
        float n0 = normals[base], n1 = normals[base + 1];
        s += 1.0f - (n0 * t0 + n1 * t1) * inv;
    }
    float r = block_reduce(s, sbuf);
    if (threadIdx.x == 0) ws[WS_TAN + idx] = r;
}

__device__ __forceinline__ void var_part(int idx, const float* __restrict__ ae,
                                         const int* __restrict__ centers,
                                         const int* __restrict__ kps,
                                         float* __restrict__ ws, float* smem) {
    int n = idx & 31, b = idx >> 5;
    float* cy = smem, *cx = smem + 32, *sbuf = smem + 64;
    if (threadIdx.x < NN) {
        int cb = (b * NN + threadIdx.x) * 2;
        cy[threadIdx.x] = centers[cb]     * (1.0f / 512.0f);
        cx[threadIdx.x] = centers[cb + 1] * (1.0f / 512.0f);
    }
    __syncthreads();
    int k = threadIdx.x;
    int kb = ((b * NN + n) * KK + k) * 2;
    int ky = kps[kb], kx = kps[kb + 1];
    int pix = ky * WIDTH + kx;
    const float* aeb = ae + (size_t)b * 4 * HW;
    float se0 = ftanh(aeb[pix])      + ky * (1.0f / 512.0f);
    float se1 = ftanh(aeb[HW + pix]) + kx * (1.0f / 512.0f);
    float sg0 = __expf(aeb[2 * HW + pix]);
    float sg1 = __expf(aeb[3 * HW + pix]);
    float own = 0.f, mx = -1e30f;
    #pragma unroll
    for (int m = 0; m < NN; ++m) {
        float d0 = se0 - cy[m], d1 = se1 - cx[m];
        float dist = __expf(-(d0 * d0 * sg0 + d1 * d1 * sg1));
        mx = fmaxf(mx, dist);
        if (m == n) own = dist;
    }
    float r = block_reduce(fabsf(own - mx), sbuf);
    if (threadIdx.x == 0) ws[WS_VAR + b * NN + n] = r;
}

// ---- the mega kernel: one dispatch for all partials ----
__global__ void __launch_bounds__(256)
k_mega(const float* __restrict__ cls_out, const float* __restrict__ wh_out,
       const float* __restrict__ kp_out,  const float* __restrict__ ae_out,
       const float* __restrict__ tan_out, const float* __restrict__ cls_mask,
       const float* __restrict__ wh_target, const float* __restrict__ wh_mask,
       const float* __restrict__ kp_mask, const float* __restrict__ ae_masks,
       const float* __restrict__ tan_normals,
       const int* __restrict__ centers, const int* __restrict__ kps,
       const int* __restrict__ tan_points, float* __restrict__ ws) {
    __shared__ float smem[256];
    int bid = blockIdx.x;
    if (bid < NBLK_INST) {
        inst_part(bid, ae_out, ae_masks, centers, ws, smem);
    } else if (bid < OFF_FOCAL) {
        wh_part(bid - OFF_WH, wh_out, wh_target, wh_mask, ws, smem);
    } else if (bid < OFF_TAN) {
        focal_part(bid - OFF_FOCAL, cls_out, cls_mask, kp_out, kp_mask, ws, smem);
    } else if (bid < OFF_VAR) {
        tan_part(bid - OFF_TAN, tan_out, tan_normals, tan_points, ws, smem);
    } else {
        var_part(bid - OFF_VAR, ae_out, centers, kps, ws, smem);
    }
}

// ---- finalize: 1 block ----
__global__ void __launch_bounds__(256)
k_final(const float* __restrict__ ws, float* __restrict__ out) {
    __shared__ float sbuf[4];
    int tid = threadIdx.x;
    float ae_v = 0.f;
    if (tid < 128) {   // tid = b*32 + n ; n = grp*8 + il ; il = ilp*2 + par
        int b = tid >> 5, n = tid & 31, grp = n >> 3, il = n & 7;
        const float* base = ws + WS_INST + (size_t)((b * 4 + grp) * 64) * 16
                            + (il >> 1) * 4 + (il & 1) * 2;
        float sum = 0.f, cnt = 0.f;
        #pragma unroll 8
        for (int seg = 0; seg < 64; ++seg) { sum += base[seg * 16]; cnt += base[seg * 16 + 1]; }
        // where(np>0, -(pos+neg)/max(np,1), -neg) == -sum/max(np,1)  (np==0 => pos==0)
        ae_v = -sum / fmaxf(cnt, 1.0f) + ws[WS_VAR + tid];
    }
    float ae_sum = block_reduce(ae_v, sbuf);

    float cls_sum = block_reduce(ws[WS_FOCAL + tid * 2], sbuf);
    float cls_cnt = block_reduce(ws[WS_FOCAL + tid * 2 + 1], sbuf);
    float kp_sum  = block_reduce(ws[WS_FOCAL + 512 + tid * 2], sbuf);
    float kp_cnt  = block_reduce(ws[WS_FOCAL + 512 + tid * 2 + 1], sbuf);
    float wh_sl   = block_reduce(ws[WS_WH + tid * 2], sbuf);
    float wh_ms   = block_reduce(ws[WS_WH + tid * 2 + 1], sbuf);
    float tan_sum = block_reduce(tid < 32 ? ws[WS_TAN + tid] : 0.f, sbuf);

    if (tid == 0) {
        float l_cls = -cls_sum / fmaxf(cls_cnt, 1.0f);
        float l_kp  = -kp_sum  / fmaxf(kp_cnt,  1.0f);
        float l_wh  = 0.1f * wh_sl / (wh_ms + 1e-4f);
        float l_ae  = ae_sum / (float)(NN * BB);
        float l_tan = tan_sum / (float)(PP * BB);
        out[0] = l_cls + l_wh + l_kp + l_ae + l_tan;
    }
}

extern "C" void kernel_launch(void* const* d_in, const int* in_sizes, int n_in,
                              void* d_out, int out_size, void* d_ws, size_t ws_size,
                              hipStream_t stream) {
    const float* cls_out     = (const float*)d_in[0];
    const float* wh_out      = (const float*)d_in[1];
    const float* kp_out      = (const float*)d_in[2];
    const float* ae_out      = (const float*)d_in[3];
    const float* tan_out     = (const float*)d_in[4];
    const float* cls_mask    = (const float*)d_in[5];
    const float* wh_target   = (const float*)d_in[6];
    const float* wh_mask     = (const float*)d_in[7];
    const float* kp_mask     = (const float*)d_in[8];
    const float* ae_masks    = (const float*)d_in[9];
    const float* tan_normals = (const float*)d_in[10];
    // d_in[11] = xym: analytic (y/512, x/512)
    const int* centers    = (const int*)d_in[12];
    const int* kps        = (const int*)d_in[13];
    const int* tan_points = (const int*)d_in[14];
    float* ws  = (float*)d_ws;
    float* out = (float*)d_out;

    k_mega<<<NBLK_TOTAL, 256, 0, stream>>>(cls_out, wh_out, kp_out, ae_out, tan_out,
                                           cls_mask, wh_target, wh_mask, kp_mask,
                                           ae_masks, tan_normals, centers, kps,
                                           tan_points, ws);
    k_final<<<1, 256, 0, stream>>>(ws, out);
}

// Round 14
// 56.759 us; speedup vs baseline: 1.4455x; 1.1958x over previous
//
#include <hip/hip_runtime.h>
#include <math.h>

#define HW     262144   // 512*512
#define WIDTH  512
#define BB     4
#define NN     32
#define KK     256
#define PP     8192
#define EPSF   1e-4f
#define ONE_M_EPS (1.0f - 1e-4f)

// ---- block partition: inst first (longest), small families fill the tail ----
#define NBLK_INST  512   // (b:4) x (grp:4 of 8 inst) x (seg:32 of 32KB plane-segment)
#define NBLK_WH    256
#define NBLK_FOCAL 512   // 2 tensors x 256
#define NBLK_TAN   32
#define NBLK_VAR   128
#define OFF_WH     NBLK_INST
#define OFF_FOCAL  (OFF_WH + NBLK_WH)
#define OFF_TAN    (OFF_FOCAL + NBLK_FOCAL)
#define OFF_VAR    (OFF_TAN + NBLK_TAN)
#define NBLK_TOTAL (OFF_VAR + NBLK_VAR)   // 1440

// ---- workspace layout (floats) ----
#define WS_INST  0       // [512 blocks][16]  (il*2 + {sum,cnt}) = 8192
#define WS_FOCAL 8192    // [2][256][2] = 1024
#define WS_WH    9216    // [256][2]    = 512
#define WS_TAN   9728    // [32]
#define WS_VAR   9760    // [128]
// total 9888 floats

__device__ __forceinline__ float ftanh(float x) {
    float e = __expf(2.0f * x);
    return 1.0f - 2.0f / (e + 1.0f);
}

__device__ __forceinline__ float wave_reduce(float v) {
    #pragma unroll
    for (int off = 1; off < 64; off <<= 1) v += __shfl_xor(v, off, 64);
    return v;
}

__device__ __forceinline__ float block_reduce(float v, float* sbuf) {
    v = wave_reduce(v);
    int lane = threadIdx.x & 63, wid = threadIdx.x >> 6;
    __syncthreads();
    if (lane == 0) sbuf[wid] = v;
    __syncthreads();
    float r = 0.f;
    if (threadIdx.x == 0) {
        for (int i = 0; i < 4; ++i) r += sbuf[i];
    }
    return r;
}

// ---- AE instance focal: R10 geometry, instance PAIRS on the proven sweep ----
// idx: b = idx>>7, grp = (idx>>5)&3 (8 instances), seg = idx&31 (32KB segment).
// 4 pairs (unroll 1); per pair: FULLY-UNROLLED 8-step sweep of the 32KB segment
// with explicit next-step prefetch on BOTH mask streams (R10's pipeline shape).
// se/sg computed once per pixel per pair (4x redundancy vs R10's 8x);
// ae re-read 4x per block (vs R10's 8x).
__device__ __forceinline__ void inst_part(int idx, const float* __restrict__ ae,
                                          const float* __restrict__ masks,
                                          const int* __restrict__ centers,
                                          float* __restrict__ ws,
                                          float* __restrict__ s_part) { // [4][16]
    const int tid = threadIdx.x, lane = tid & 63, w = tid >> 6;
    const int b = idx >> 7, grp = (idx >> 5) & 3, seg = idx & 31;
    const float4* aeb   = (const float4*)ae + (size_t)b * 4 * 65536;
    const float4* mbase = (const float4*)masks + ((size_t)(b * NN + grp * 8) << 16);
    const int segf4 = seg * 2048;     // 2048 f4 = 32KB
    const int* cb = centers + (b * NN + grp * 8) * 2;

    #pragma unroll 1
    for (int ilp = 0; ilp < 4; ++ilp) {
        const int il0 = ilp * 2, il1 = il0 + 1;
        float cy0 = (float)cb[il0 * 2]     * (1.0f / 512.0f);   // wave-uniform
        float cx0 = (float)cb[il0 * 2 + 1] * (1.0f / 512.0f);
        float cy1 = (float)cb[il1 * 2]     * (1.0f / 512.0f);
        float cx1 = (float)cb[il1 * 2 + 1] * (1.0f / 512.0f);
        const float4* mp0 = mbase + ((size_t)il0 << 16) + segf4;
        const float4* mp1 = mbase + ((size_t)il1 << 16) + segf4;
        float sum0 = 0.f, cnt0 = 0.f, sum1 = 0.f, cnt1 = 0.f;
        float4 mk0 = mp0[tid];
        float4 mk1 = mp1[tid];
        #pragma unroll
        for (int it = 0; it < 8; ++it) {
            float4 mk0n, mk1n;
            if (it < 7) {
                mk0n = mp0[(it + 1) * 256 + tid];   // sequential prefetch, stream 0
                mk1n = mp1[(it + 1) * 256 + tid];   // sequential prefetch, stream 1
            }
            int v = segf4 + it * 256 + tid;
            float4 a0 = aeb[v];
            float4 a1 = aeb[65536 + v];
            float4 a2 = aeb[131072 + v];
            float4 a3 = aeb[196608 + v];
            int pix0 = v * 4;
            float fy  = (float)(pix0 >> 9)  * (1.0f / 512.0f);
            float fx0 = (float)(pix0 & 511) * (1.0f / 512.0f);
            #pragma unroll
            for (int j = 0; j < 4; ++j) {
                float se0 = ftanh((&a0.x)[j]) + fy;
                float se1 = ftanh((&a1.x)[j]) + fx0 + (float)j * (1.0f / 512.0f);
                float sg0 = __expf((&a2.x)[j]);
                float sg1 = __expf((&a3.x)[j]);
                // instance il0
                {
                    float m  = (&mk0.x)[j];                // exactly 0.0 or 1.0
                    float dy = se0 - cy0, dx = se1 - cx0;
                    float s  = fmaf(dx * dx, sg1, dy * dy * sg0);
                    float e  = __expf(-s);
                    float pc = fminf(fmaxf(e, EPSF), ONE_M_EPS);
                    float omp = 1.0f - pc;
                    // pos: log(pc)*omp^2 ; neg: log(omp)*pc^2 (neg_w==1, binary)
                    float A = (m != 0.f) ? pc : omp;
                    float B = 1.0f - A;
                    sum0 = fmaf(__logf(A), B * B, sum0);
                    cnt0 += m;
                }
                // instance il1
                {
                    float m  = (&mk1.x)[j];
                    float dy = se0 - cy1, dx = se1 - cx1;
                    float s  = fmaf(dx * dx, sg1, dy * dy * sg0);
                    float e  = __expf(-s);
                    float pc = fminf(fmaxf(e, EPSF), ONE_M_EPS);
                    float omp = 1.0f - pc;
                    float A = (m != 0.f) ? pc : omp;
                    float B = 1.0f - A;
                    sum1 = fmaf(__logf(A), B * B, sum1);
                    cnt1 += m;
                }
            }
            mk0 = mk0n;
            mk1 = mk1n;
        }
        float r0 = wave_reduce(sum0);
        float r1 = wave_reduce(cnt0);
        float r2 = wave_reduce(sum1);
        float r3 = wave_reduce(cnt1);
        if (lane == 0) {
            s_part[w * 16 + il0 * 2 + 0] = r0;
            s_part[w * 16 + il0 * 2 + 1] = r1;
            s_part[w * 16 + il1 * 2 + 0] = r2;
            s_part[w * 16 + il1 * 2 + 1] = r3;
        }
    }
    __syncthreads();
    if (tid < 16) {
        float s = s_part[tid] + s_part[16 + tid] + s_part[32 + tid] + s_part[48 + tid];
        ws[WS_INST + idx * 16 + tid] = s;
    }
}

// ---- cls/kp focal: idx = t*256 + blk, 4 iters ----
__device__ __forceinline__ void focal_part(int idx, const float* __restrict__ cls_out,
                                           const float* __restrict__ cls_mask,
                                           const float* __restrict__ kp_out,
                                           const float* __restrict__ kp_mask,
                                           float* __restrict__ ws, float* sbuf) {
    int t = idx >> 8, blk = idx & 255;
    const float4* po = (const float4*)(t == 0 ? cls_out : kp_out);
    const float4* pm = (const float4*)(t == 0 ? cls_mask : kp_mask);
    float sum = 0.f, cnt = 0.f;
    #pragma unroll
    for (int it = 0; it < 4; ++it) {
        int i = blk * 256 + threadIdx.x + it * 65536;
        float4 xo = po[i], xm = pm[i];
        #pragma unroll
        for (int j = 0; j < 4; ++j) {
            float x = (&xo.x)[j], gt = (&xm.x)[j];
            float p = 1.0f / (1.0f + __expf(-x));
            p = fminf(fmaxf(p, EPSF), ONE_M_EPS);
            float omp = 1.0f - p;
            float pos_t = __logf(p) * omp * omp;
            float og = 1.0f - gt;
            float negw = og * og; negw *= negw;
            float neg_t = __logf(omp) * p * p * negw;
            bool ispos = (gt == 1.0f);
            sum += ispos ? pos_t : neg_t;
            cnt += ispos ? 1.0f : 0.0f;
        }
    }
    float r0 = block_reduce(sum, sbuf);
    float r1 = block_reduce(cnt, sbuf);
    if (threadIdx.x == 0) {
        ws[WS_FOCAL + idx * 2 + 0] = r0;
        ws[WS_FOCAL + idx * 2 + 1] = r1;
    }
}

__device__ __forceinline__ void wh_part(int blk, const float* __restrict__ o,
                                        const float* __restrict__ tg,
                                        const float* __restrict__ m,
                                        float* __restrict__ ws, float* sbuf) {
    const float4* po  = (const float4*)o;
    const float4* pt  = (const float4*)tg;
    const float4* pmk = (const float4*)m;
    float sl = 0.f, ms = 0.f;
    #pragma unroll
    for (int it = 0; it < 8; ++it) {
        int i = blk * 256 + threadIdx.x + it * 65536;
        float4 a = po[i], b = pt[i], c = pmk[i];
        #pragma unroll
        for (int j = 0; j < 4; ++j) {
            float mm = (&c.x)[j];
            float d  = (&a.x)[j] * mm - (&b.x)[j] * mm;
            float ad = fabsf(d);
            sl += (ad < 1.0f) ? 0.5f * d * d : (ad - 0.5f);
            ms += mm;
        }
    }
    float r0 = block_reduce(sl, sbuf);
    float r1 = block_reduce(ms, sbuf);
    if (threadIdx.x == 0) {
        ws[WS_WH + blk * 2 + 0] = r0;
        ws[WS_WH + blk * 2 + 1] = r1;
    }
}

__device__ __forceinline__ void tan_part(int idx, const float* __restrict__ tan_out,
                                         const float* __restrict__ normals,
                                         const int* __restrict__ pts,
                                         float* __restrict__ ws, float* sbuf) {
    int b = idx >> 3, seg = idx & 7;
    float s = 0.f;
    for (int p = seg * 1024 + threadIdx.x; p < seg * 1024 + 1024; p += 256) {
        int base = (b * PP + p) * 2;
        int py = pts[base], px = pts[base + 1];
        int pix = py * WIDTH + px;
        float t0 = tan_out[b * 2 * HW + pix];
        float t1 = tan_out[b * 2 * HW + HW + pix];
        float inv = 1.0f / fmaxf(sqrtf(t0 * t0 + t1 * t1), EPSF);
        float n0 = normals[base], n1 = normals[base + 1];
        s += 1.0f - (n0 * t0 + n1 * t1) * inv;
    }
    float r = block_reduce(s, sbuf);
    if (threadIdx.x == 0) ws[WS_TAN + idx] = r;
}

__device__ __forceinline__ void var_part(int idx, const float* __restrict__ ae,
                                         const int* __restrict__ centers,
                                         const int* __restrict__ kps,
                                         float* __restrict__ ws, float* smem) {
    int n = idx & 31, b = idx >> 5;
    float* cy = smem, *cx = smem + 32, *sbuf = smem + 64;
    if (threadIdx.x < NN) {
        int cb = (b * NN + threadIdx.x) * 2;
        cy[threadIdx.x] = centers[cb]     * (1.0f / 512.0f);
        cx[threadIdx.x] = centers[cb + 1] * (1.0f / 512.0f);
    }
    __syncthreads();
    int k = threadIdx.x;
    int kb = ((b * NN + n) * KK + k) * 2;
    int ky = kps[kb], kx = kps[kb + 1];
    int pix = ky * WIDTH + kx;
    const float* aeb = ae + (size_t)b * 4 * HW;
    float se0 = ftanh(aeb[pix])      + ky * (1.0f / 512.0f);
    float se1 = ftanh(aeb[HW + pix]) + kx * (1.0f / 512.0f);
    float sg0 = __expf(aeb[2 * HW + pix]);
    float sg1 = __expf(aeb[3 * HW + pix]);
    float own = 0.f, mx = -1e30f;
    #pragma unroll
    for (int m = 0; m < NN; ++m) {
        float d0 = se0 - cy[m], d1 = se1 - cx[m];
        float dist = __expf(-(d0 * d0 * sg0 + d1 * d1 * sg1));
        mx = fmaxf(mx, dist);
        if (m == n) own = dist;
    }
    float r = block_reduce(fabsf(own - mx), sbuf);
    if (threadIdx.x == 0) ws[WS_VAR + b * NN + n] = r;
}

// ---- the mega kernel: one dispatch for all partials ----
__global__ void __launch_bounds__(256)
k_mega(const float* __restrict__ cls_out, const float* __restrict__ wh_out,
       const float* __restrict__ kp_out,  const float* __restrict__ ae_out,
       const float* __restrict__ tan_out, const float* __restrict__ cls_mask,
       const float* __restrict__ wh_target, const float* __restrict__ wh_mask,
       const float* __restrict__ kp_mask, const float* __restrict__ ae_masks,
       const float* __restrict__ tan_normals,
       const int* __restrict__ centers, const int* __restrict__ kps,
       const int* __restrict__ tan_points, float* __restrict__ ws) {
    __shared__ float smem[256];
    int bid = blockIdx.x;
    if (bid < NBLK_INST) {
        inst_part(bid, ae_out, ae_masks, centers, ws, smem);
    } else if (bid < OFF_FOCAL) {
        wh_part(bid - OFF_WH, wh_out, wh_target, wh_mask, ws, smem);
    } else if (bid < OFF_TAN) {
        focal_part(bid - OFF_FOCAL, cls_out, cls_mask, kp_out, kp_mask, ws, smem);
    } else if (bid < OFF_VAR) {
        tan_part(bid - OFF_TAN, tan_out, tan_normals, tan_points, ws, smem);
    } else {
        var_part(bid - OFF_VAR, ae_out, centers, kps, ws, smem);
    }
}

// ---- finalize: 1 block ----
__global__ void __launch_bounds__(256)
k_final(const float* __restrict__ ws, float* __restrict__ out) {
    __shared__ float sbuf[4];
    int tid = threadIdx.x;
    float ae_v = 0.f;
    if (tid < 128) {   // tid = b*32 + n ; n = grp*8 + i
        int b = tid >> 5, n = tid & 31, grp = n >> 3, i = n & 7;
        const float* base = ws + WS_INST + ((b * 4 + grp) * 32) * 16 + i * 2;
        float sum = 0.f, cnt = 0.f;
        #pragma unroll 8
        for (int seg = 0; seg < 32; ++seg) { sum += base[seg * 16]; cnt += base[seg * 16 + 1]; }
        // where(np>0, -(pos+neg)/max(np,1), -neg) == -sum/max(np,1)  (np==0 => pos==0)
        ae_v = -sum / fmaxf(cnt, 1.0f) + ws[WS_VAR + tid];
    }
    float ae_sum = block_reduce(ae_v, sbuf);

    float cls_sum = block_reduce(ws[WS_FOCAL + tid * 2], sbuf);
    float cls_cnt = block_reduce(ws[WS_FOCAL + tid * 2 + 1], sbuf);
    float kp_sum  = block_reduce(ws[WS_FOCAL + 512 + tid * 2], sbuf);
    float kp_cnt  = block_reduce(ws[WS_FOCAL + 512 + tid * 2 + 1], sbuf);
    float wh_sl   = block_reduce(ws[WS_WH + tid * 2], sbuf);
    float wh_ms   = block_reduce(ws[WS_WH + tid * 2 + 1], sbuf);
    float tan_sum = block_reduce(tid < 32 ? ws[WS_TAN + tid] : 0.f, sbuf);

    if (tid == 0) {
        float l_cls = -cls_sum / fmaxf(cls_cnt, 1.0f);
        float l_kp  = -kp_sum  / fmaxf(kp_cnt,  1.0f);
        float l_wh  = 0.1f * wh_sl / (wh_ms + 1e-4f);
        float l_ae  = ae_sum / (float)(NN * BB);
        float l_tan = tan_sum / (float)(PP * BB);
        out[0] = l_cls + l_wh + l_kp + l_ae + l_tan;
    }
}

extern "C" void kernel_launch(void* const* d_in, const int* in_sizes, int n_in,
                              void* d_out, int out_size, void* d_ws, size_t ws_size,
                              hipStream_t stream) {
    const float* cls_out     = (const float*)d_in[0];
    const float* wh_out      = (const float*)d_in[1];
    const float* kp_out      = (const float*)d_in[2];
    const float* ae_out      = (const float*)d_in[3];
    const float* tan_out     = (const float*)d_in[4];
    const float* cls_mask    = (const float*)d_in[5];
    const float* wh_target   = (const float*)d_in[6];
    const float* wh_mask     = (const float*)d_in[7];
    const float* kp_mask     = (const float*)d_in[8];
    const float* ae_masks    = (const float*)d_in[9];
    const float* tan_normals = (const float*)d_in[10];
    // d_in[11] = xym: analytic (y/512, x/512)
    const int* centers    = (const int*)d_in[12];
    const int* kps        = (const int*)d_in[13];
    const int* tan_points = (const int*)d_in[14];
    float* ws  = (float*)d_ws;
    float* out = (float*)d_out;

    k_mega<<<NBLK_TOTAL, 256, 0, stream>>>(cls_out, wh_out, kp_out, ae_out, tan_out,
                                           cls_mask, wh_target, wh_mask, kp_mask,
                                           ae_masks, tan_normals, centers, kps,
                                           tan_points, ws);
    k_final<<<1, 256, 0, stream>>>(ws, out);
}